// Round 5
// baseline (169.774 us; speedup 1.0000x reference)
//
#include <hip/hip_runtime.h>
#include <hip/hip_bf16.h>
#include <math.h>

#define LEN 128
#define NCELLS 8256          // LEN*(LEN+1)/2
#define TOTAL 349504         // sum_{l=1}^{127} (128-l)*l
#define NCONSTR 8
#define BONUS 1000.0f
#define NT 512
#define TB_TOTAL 15912       // score count for levels 112..127
#define TB_SOFF 333592       // TOTAL - TB_TOTAL
#define TB_VEC 3978          // TB_TOTAL / 4

// Barrier WITHOUT vmcnt drain: only LDS writes must be ordered; register
// prefetch loads stay in flight across the barrier (T4 discipline).
__device__ __forceinline__ void level_barrier() {
    __builtin_amdgcn_sched_barrier(0);
    asm volatile("s_waitcnt lgkmcnt(0)\n\ts_barrier" ::: "memory");
    __builtin_amdgcn_sched_barrier(0);
}

// DPP quad_perm cross-lane max (VALU pipe, no LDS traffic).
__device__ __forceinline__ float dpp_xor1_max(float v) {
    int r = __builtin_amdgcn_update_dpp(0, __float_as_int(v), 0xB1, 0xF, 0xF, true);
    return fmaxf(v, __int_as_float(r));
}
__device__ __forceinline__ float dpp_xor2_max(float v) {
    int r = __builtin_amdgcn_update_dpp(0, __float_as_int(v), 0x4E, 0xF, 0xF, true);
    return fmaxf(v, __int_as_float(r));
}

template<int LG>
__device__ __forceinline__ void redmax2(float& a, float& b) {
    #pragma unroll
    for (int mm = (1 << LG) >> 1; mm >= 4; mm >>= 1) {
        a = fmaxf(a, __shfl_xor(a, mm));
        b = fmaxf(b, __shfl_xor(b, mm));
    }
    if constexpr (LG >= 2) { a = dpp_xor2_max(a); b = dpp_xor2_max(b); }
    if constexpr (LG >= 1) { a = dpp_xor1_max(a); b = dpp_xor1_max(b); }
}

// One CKY level. Phase 1: issue all 2*JM independent ds_read_b64 into register
// arrays; phase 2: consume. Prefetch block loads scores for level+2 into rnxt
// (2-deep pipeline; loads cross two barriers before consumption).
template<int LG, int LG2, int JM, int JM2>
__device__ __forceinline__ void lstep(const int level, int& soff,
        const float* __restrict__ g, float2* __restrict__ chart,
        float (&rcur)[16], float (&rnxt)[16], const int tid)
{
    const int N = level;
    const int L = LEN - level;
    constexpr int T = 1 << LG;
    const int pos = tid >> LG;
    const int sub = tid & (T - 1);
    const int soff_n = soff + L * N;

    // ---- issue score loads for level+2 (consumed after two barriers) ----
    if constexpr (LG2 >= 0) {
        constexpr int T2 = 1 << LG2;
        const int N2 = level + 2;
        const int L2 = L - 2;
        const int soff_nn = soff_n + (L - 1) * (N + 1);
        const int pos2 = tid >> LG2;
        const int sub2 = tid & (T2 - 1);
        if (pos2 < L2) {
            const float* __restrict__ gp = g + soff_nn + pos2 * N2 + sub2;
            #pragma unroll
            for (int j = 0; j < JM2; j++) {
                if (sub2 + j * T2 < N2) rnxt[j] = gp[j * T2];
            }
        }
    }

    // ---- compute this level ----
    float bp = -INFINITY, bc = -INFINITY;
    if (pos < L) {
        const int jml = (N - sub + T - 1) >> LG;   // per-lane valid trip count
        float2 lv[JM], rv[JM];
        float  xs[JM];
        #pragma unroll
        for (int j = 0; j < JM; j++) {
            const int n = sub + j * T;
            const int m = level - 1 - n;
            const bool v = (j < jml);
            const int l_idx = ((n * (257 - n)) >> 1) + pos;
            int r_idx = ((m * (257 - m)) >> 1) + pos + n + 1;
            r_idx = v ? r_idx : 0;
            lv[j] = chart[l_idx];
            rv[j] = chart[r_idx];
            xs[j] = v ? rcur[j] : -INFINITY;
        }
        #pragma unroll
        for (int j = 0; j < JM; j++) {
            bp = fmaxf(bp, lv[j].x + rv[j].x + xs[j]);
            bc = fmaxf(bc, lv[j].y + rv[j].y + xs[j]);
        }
    }
    redmax2<LG>(bp, bc);
    if (pos < L && sub == 0) {
        const int q = ((level * (257 - level)) >> 1) + pos;
        float2 c = chart[q];
        c.x += bp;
        c.y += bc;
        chart[q] = c;
    }
    level_barrier();
    soff = soff_n;
}

// 4 levels at TPP=4, JM=K exactly (levels 4K-3..4K). Buffer rotation:
// (X fetch Z),(Y fetch X),(Z fetch Y),(X fetch Z); next seg starts at Y.
template<int K>
__device__ __forceinline__ void seg4(int& soff, const float* __restrict__ g,
        float2* __restrict__ chart, float (&X)[16], float (&Y)[16], float (&Z)[16],
        const int tid)
{
    lstep<2,2,K,K>  (4*K-3, soff, g, chart, X, Z, tid);
    lstep<2,2,K,K>  (4*K-2, soff, g, chart, Y, X, tid);
    lstep<2,2,K,K+1>(4*K-1, soff, g, chart, Z, Y, tid);
    lstep<2,2,K,K+1>(4*K,   soff, g, chart, X, Z, tid);
}

// Single-wave tail level (wave 0 only, NO barriers; DS pipe is in-order per
// wave, so chart write->read across levels is safe). Scores come from LDS.
template<int LGT>
__device__ __forceinline__ void tail_level(const int level, int& tb,
        float2* __restrict__ chart, const float* __restrict__ sc, const int lane)
{
    const int N = level, L = LEN - level;
    constexpr int T = 1 << LGT;
    const int pos = lane >> LGT;
    const int sub = lane & (T - 1);
    const bool act = (pos < L);
    const int jmax = (N + T - 1) >> LGT;
    const int base = tb + pos * N;
    float bp = -INFINITY, bc = -INFINITY;
    #pragma unroll 4
    for (int j = 0; j < jmax; j++) {
        const int n = sub + j * T;
        const bool v = act && (n < N);
        const int m = level - 1 - n;
        int l_idx = ((n * (257 - n)) >> 1) + pos;
        int r_idx = ((m * (257 - m)) >> 1) + pos + n + 1;
        l_idx = v ? l_idx : 0;
        r_idx = v ? r_idx : 0;
        const float2 lv = chart[l_idx];
        const float2 rv = chart[r_idx];
        const float x = v ? sc[base + (n < N ? n : 0)] : -INFINITY;
        bp = fmaxf(bp, lv.x + rv.x + x);
        bc = fmaxf(bc, lv.y + rv.y + x);
    }
    redmax2<LGT>(bp, bc);
    if (act && sub == 0) {
        const int q = ((level * (257 - level)) >> 1) + pos;
        float2 c = chart[q];
        c.x += bp;
        c.y += bc;
        chart[q] = c;
    }
    asm volatile("s_waitcnt lgkmcnt(0)" ::: "memory");
    tb += L * N;
}

__global__ __launch_bounds__(NT)
void cky_fused_kernel(const float* __restrict__ scores,
                      const int* __restrict__ cpos,
                      float* __restrict__ ws)
{
    __shared__ float2 chart[NCELLS];     // .x = pred chart, .y = constr chart
    __shared__ float4 sc4[TB_VEC];       // staged scores for levels 112..127

    const int b   = blockIdx.x;
    const int tid = threadIdx.x;
    const float* __restrict__ g = scores + (size_t)b * TOTAL;

    float rA[16], rB[16], rC[16];

    // ---- issue tail-score staging loads FIRST (vectorized, coalesced) ----
    float4 tt[8];
    {
        const float4* __restrict__ g4 = (const float4*)(g + TB_SOFF);
        #pragma unroll
        for (int k = 0; k < 8; k++) {
            const int i4 = tid + (k << 9);
            if (i4 < TB_VEC) tt[k] = g4[i4];
        }
    }
    // ---- prefetch level 1 (into rA) and level 2 (into rB) scores ----
    {
        const int pos = tid >> 2;
        const int sub = tid & 3;
        if (pos < 127 && sub == 0) rA[0] = g[pos];
        if (pos < 126 && sub < 2)  rB[0] = g[127 + pos * 2 + sub];
    }
    int cp = 0;
    if (tid < NCONSTR) cp = cpos[b * NCONSTR + tid];

    // ---- init both charts (overlaps with global-load latency) ----
    for (int i = tid; i < NCELLS; i += NT) chart[i] = make_float2(0.f, 0.f);
    // ---- write staged tail scores to LDS ----
    #pragma unroll
    for (int k = 0; k < 8; k++) {
        const int i4 = tid + (k << 9);
        if (i4 < TB_VEC) sc4[i4] = tt[k];
    }
    level_barrier();
    if (tid < NCONSTR) chart[cp].y = BONUS;   // set (not add); duplicates benign
    level_barrier();

    int soff = 0;

    // ---- TPP=4: levels 1..60 (triple-buffer rotation, period 3 in K) ----
    seg4<1>(soff, g, chart, rA, rB, rC, tid);
    seg4<2>(soff, g, chart, rB, rC, rA, tid);
    seg4<3>(soff, g, chart, rC, rA, rB, tid);
    seg4<4>(soff, g, chart, rA, rB, rC, tid);
    seg4<5>(soff, g, chart, rB, rC, rA, tid);
    seg4<6>(soff, g, chart, rC, rA, rB, tid);
    seg4<7>(soff, g, chart, rA, rB, rC, tid);
    seg4<8>(soff, g, chart, rB, rC, rA, tid);
    seg4<9>(soff, g, chart, rC, rA, rB, tid);
    seg4<10>(soff, g, chart, rA, rB, rC, tid);
    seg4<11>(soff, g, chart, rB, rC, rA, tid);
    seg4<12>(soff, g, chart, rC, rA, rB, tid);
    seg4<13>(soff, g, chart, rA, rB, rC, tid);
    seg4<14>(soff, g, chart, rB, rC, rA, tid);
    seg4<15>(soff, g, chart, rC, rA, rB, tid);
    // ---- TPP=4 tail levels 61..63 ----
    lstep<2,2,16,16>(61, soff, g, chart, rA, rC, tid);
    lstep<2,3,16,8> (62, soff, g, chart, rB, rA, tid);
    lstep<2,3,16,9> (63, soff, g, chart, rC, rB, tid);
    // ---- TPP=8: levels 64..95 ----
    lstep<3,3,8,9>  (64, soff, g, chart, rA, rC, tid);
    lstep<3,3,9,9>  (65, soff, g, chart, rB, rA, tid);
    lstep<3,3,9,9>  (66, soff, g, chart, rC, rB, tid);
    lstep<3,3,9,9>  (67, soff, g, chart, rA, rC, tid);
    lstep<3,3,9,9>  (68, soff, g, chart, rB, rA, tid);
    lstep<3,3,9,9>  (69, soff, g, chart, rC, rB, tid);
    lstep<3,3,9,9>  (70, soff, g, chart, rA, rC, tid);
    lstep<3,3,9,10> (71, soff, g, chart, rB, rA, tid);
    lstep<3,3,9,10> (72, soff, g, chart, rC, rB, tid);
    lstep<3,3,10,10>(73, soff, g, chart, rA, rC, tid);
    lstep<3,3,10,10>(74, soff, g, chart, rB, rA, tid);
    lstep<3,3,10,10>(75, soff, g, chart, rC, rB, tid);
    lstep<3,3,10,10>(76, soff, g, chart, rA, rC, tid);
    lstep<3,3,10,10>(77, soff, g, chart, rB, rA, tid);
    lstep<3,3,10,10>(78, soff, g, chart, rC, rB, tid);
    lstep<3,3,10,11>(79, soff, g, chart, rA, rC, tid);
    lstep<3,3,10,11>(80, soff, g, chart, rB, rA, tid);
    lstep<3,3,11,11>(81, soff, g, chart, rC, rB, tid);
    lstep<3,3,11,11>(82, soff, g, chart, rA, rC, tid);
    lstep<3,3,11,11>(83, soff, g, chart, rB, rA, tid);
    lstep<3,3,11,11>(84, soff, g, chart, rC, rB, tid);
    lstep<3,3,11,11>(85, soff, g, chart, rA, rC, tid);
    lstep<3,3,11,11>(86, soff, g, chart, rB, rA, tid);
    lstep<3,3,11,12>(87, soff, g, chart, rC, rB, tid);
    lstep<3,3,11,12>(88, soff, g, chart, rA, rC, tid);
    lstep<3,3,12,12>(89, soff, g, chart, rB, rA, tid);
    lstep<3,3,12,12>(90, soff, g, chart, rC, rB, tid);
    lstep<3,3,12,12>(91, soff, g, chart, rA, rC, tid);
    lstep<3,3,12,12>(92, soff, g, chart, rB, rA, tid);
    lstep<3,3,12,12>(93, soff, g, chart, rC, rB, tid);
    lstep<3,4,12,6> (94, soff, g, chart, rA, rC, tid);
    lstep<3,4,12,7> (95, soff, g, chart, rB, rA, tid);
    // ---- TPP=16: levels 96..111 ----
    lstep<4,4,6,7>  (96, soff, g, chart, rC, rB, tid);
    lstep<4,4,7,7>  (97, soff, g, chart, rA, rC, tid);
    lstep<4,4,7,7>  (98, soff, g, chart, rB, rA, tid);
    lstep<4,4,7,7>  (99, soff, g, chart, rC, rB, tid);
    lstep<4,4,7,7> (100, soff, g, chart, rA, rC, tid);
    lstep<4,4,7,7> (101, soff, g, chart, rB, rA, tid);
    lstep<4,4,7,7> (102, soff, g, chart, rC, rB, tid);
    lstep<4,4,7,7> (103, soff, g, chart, rA, rC, tid);
    lstep<4,4,7,7> (104, soff, g, chart, rB, rA, tid);
    lstep<4,4,7,7> (105, soff, g, chart, rC, rB, tid);
    lstep<4,4,7,7> (106, soff, g, chart, rA, rC, tid);
    lstep<4,4,7,7> (107, soff, g, chart, rB, rA, tid);
    lstep<4,4,7,7> (108, soff, g, chart, rC, rB, tid);
    lstep<4,4,7,7> (109, soff, g, chart, rA, rC, tid);
    lstep<4,-1,7,0>(110, soff, g, chart, rB, rA, tid);
    lstep<4,-1,7,0>(111, soff, g, chart, rC, rB, tid);

    // ---- waves 1..7 done; wave 0 runs levels 112..127 barrier-free ----
    if (tid >= 64) return;
    {
        const float* __restrict__ sc = (const float*)sc4;
        int tb = 0;
        #pragma unroll 1
        for (int l = 112; l < 120; ++l) tail_level<2>(l, tb, chart, sc, tid);
        #pragma unroll 1
        for (int l = 120; l < 124; ++l) tail_level<3>(l, tb, chart, sc, tid);
        tail_level<4>(124, tb, chart, sc, tid);
        tail_level<4>(125, tb, chart, sc, tid);
        tail_level<5>(126, tb, chart, sc, tid);
        tail_level<6>(127, tb, chart, sc, tid);
    }

    // ---- per-batch hinge contribution ----
    if (tid == 0) {
        const float2 f = chart[NCELLS - 1];
        const float pred   = f.x;
        const float constr = f.y - BONUS * NCONSTR;
        const float diff   = pred - constr;
        const float mask   = (fabsf(diff) >= 0.001f) ? 1.f : 0.f;
        const float hinge  = fmaxf(1.0f + diff, 0.f) * mask;
        atomicAdd(ws + 0, hinge);
        atomicAdd(ws + 1, mask);
    }
}

__global__ void final_kernel(const float* __restrict__ ws, float* __restrict__ out) {
    const float h = ws[0];
    const float m = ws[1];
    out[0] = (m > 0.1f) ? (h / fmaxf(m, 1.f)) : h;
}

extern "C" void kernel_launch(void* const* d_in, const int* in_sizes, int n_in,
                              void* d_out, int out_size, void* d_ws, size_t ws_size,
                              hipStream_t stream) {
    const float* scores = (const float*)d_in[0];
    const int*   cpos   = (const int*)d_in[1];
    float* out = (float*)d_out;
    float* ws  = (float*)d_ws;

    hipMemsetAsync(ws, 0, 2 * sizeof(float), stream);
    cky_fused_kernel<<<dim3(256), dim3(NT), 0, stream>>>(scores, cpos, ws);
    final_kernel<<<dim3(1), dim3(1), 0, stream>>>(ws, out);
}